// Round 3
// baseline (557.210 us; speedup 1.0000x reference)
//
#include <hip/hip_runtime.h>
#include <hip/hip_bf16.h>

#define T_TOK 4096
#define H_DIM 2048
#define I_DIM 768
#define E_NUM 8

typedef __attribute__((ext_vector_type(8))) short bf16x8;
typedef __attribute__((ext_vector_type(4))) float f32x4;

__device__ __forceinline__ unsigned short f2bf(float f) {
  union { float f; unsigned int u; } c; c.f = f;
  unsigned int r = c.u + 0x7fffu + ((c.u >> 16) & 1u);
  return (unsigned short)(r >> 16);
}

// ---------------- Router: logits, top-2, expert binning ----------------
__global__ __launch_bounds__(256) void router_kernel(
    const float* __restrict__ x,               // [T,H] f32
    const float* __restrict__ wr,              // [H,E] f32
    float* __restrict__ logits_out,            // [T,E] f32 (d_out tail)
    int* __restrict__ counts,                  // [E]
    int* __restrict__ entries,                 // [E][T] pair-slot p = t*2+k
    float* __restrict__ entry_w)               // [E][T]
{
  const int t = blockIdx.x;
  const int tid = threadIdx.x;
  float acc[E_NUM];
#pragma unroll
  for (int e = 0; e < E_NUM; ++e) acc[e] = 0.f;

  float xr[8];
  *(float4*)&xr[0] = *(const float4*)(x + (size_t)t * H_DIM + tid * 8);
  *(float4*)&xr[4] = *(const float4*)(x + (size_t)t * H_DIM + tid * 8 + 4);
#pragma unroll
  for (int j = 0; j < 8; ++j) {
    float xf = xr[j];
    float wv[8];
    *(float4*)&wv[0] = *(const float4*)(wr + (size_t)(tid * 8 + j) * E_NUM);
    *(float4*)&wv[4] = *(const float4*)(wr + (size_t)(tid * 8 + j) * E_NUM + 4);
#pragma unroll
    for (int e = 0; e < E_NUM; ++e) acc[e] = fmaf(xf, wv[e], acc[e]);
  }
#pragma unroll
  for (int off = 32; off > 0; off >>= 1) {
#pragma unroll
    for (int e = 0; e < E_NUM; ++e) acc[e] += __shfl_down(acc[e], off);
  }
  __shared__ float red[4][E_NUM];
  __shared__ float lf[E_NUM];
  const int wv_id = tid >> 6, lane = tid & 63;
  if (lane == 0) {
#pragma unroll
    for (int e = 0; e < E_NUM; ++e) red[wv_id][e] = acc[e];
  }
  __syncthreads();
  if (tid < E_NUM) {
    float l = red[0][tid] + red[1][tid] + red[2][tid] + red[3][tid];
    lf[tid] = l;
    logits_out[(size_t)t * E_NUM + tid] = l;   // f32 logits
  }
  __syncthreads();
  if (tid == 0) {
    int i1 = 0; float m1 = lf[0];
#pragma unroll
    for (int e = 1; e < E_NUM; ++e) if (lf[e] > m1) { m1 = lf[e]; i1 = e; }
    int i2 = -1; float m2 = -3.4e38f;
#pragma unroll
    for (int e = 0; e < E_NUM; ++e) if (e != i1 && lf[e] > m2) { m2 = lf[e]; i2 = e; }
    // normalized top-2 weights == softmax over {l1,l2}
    float w1 = 1.f / (1.f + __expf(m2 - m1));
    float w2 = 1.f - w1;
    int p1 = atomicAdd(&counts[i1], 1);
    entries[i1 * T_TOK + p1] = t * 2;
    entry_w[i1 * T_TOK + p1] = w1;
    int p2 = atomicAdd(&counts[i2], 1);
    entries[i2 * T_TOK + p2] = t * 2 + 1;
    entry_w[i2 * T_TOK + p2] = w2;
  }
}

// ---------------- Up-projection: act[p,:] = silu(x Wg) * (x Wu) ----------------
__global__ __launch_bounds__(256) void moe_up_kernel(
    const float* __restrict__ x,    // [T,H] f32
    const float* __restrict__ wi0,  // [E,H,I] f32
    const float* __restrict__ wi1,  // [E,H,I] f32
    const int* __restrict__ counts,
    const int* __restrict__ entries,
    unsigned short* __restrict__ act)        // [T*2, I] bf16
{
  const int e = blockIdx.z;
  const int cnt = counts[e];
  const int m0 = blockIdx.y * 64;
  if (m0 >= cnt) return;
  const int n0 = blockIdx.x * 64;
  const int tid = threadIdx.x;

  __shared__ __align__(16) unsigned short As[64][72];  // [m][k]
  __shared__ __align__(16) unsigned short Bg[64][72];  // [n][k] (transposed)
  __shared__ __align__(16) unsigned short Bu[64][72];
  __shared__ int rowp[64];

  if (tid < 64) rowp[tid] = (m0 + tid < cnt) ? entries[e * T_TOK + m0 + tid] : -1;
  __syncthreads();

  const float* wg_base = wi0 + (size_t)e * H_DIM * I_DIM + n0;
  const float* wu_base = wi1 + (size_t)e * H_DIM * I_DIM + n0;

  f32x4 accg[2][2], accu[2][2];
#pragma unroll
  for (int i = 0; i < 2; ++i)
#pragma unroll
    for (int j = 0; j < 2; ++j) {
      accg[i][j] = (f32x4){0.f, 0.f, 0.f, 0.f};
      accu[i][j] = (f32x4){0.f, 0.f, 0.f, 0.f};
    }

  const int wv = tid >> 6;
  const int lane = tid & 63;
  const int msub = (wv >> 1) * 32;
  const int nsub = (wv & 1) * 32;
  const int fm = lane & 15;
  const int fq = lane >> 4;

  const int arow = tid >> 3;          // 0..31
  const int acol = (tid & 7) * 8;     // 0..56
  const int k2 = (tid >> 3) * 2;      // 0..62
  const int n8 = (tid & 7) * 8;       // 0..56

  for (int kt = 0; kt < H_DIM; kt += 64) {
    // stage A (gathered token rows, f32 -> bf16)
#pragma unroll
    for (int it = 0; it < 2; ++it) {
      int r = arow + it * 32;
      int p = rowp[r];
      union { uint4 u; unsigned short h[8]; } o;
      o.u = (uint4){0u, 0u, 0u, 0u};
      if (p >= 0) {
        int t = p >> 1;
        float av[8];
        *(float4*)&av[0] = *(const float4*)(x + (size_t)t * H_DIM + kt + acol);
        *(float4*)&av[4] = *(const float4*)(x + (size_t)t * H_DIM + kt + acol + 4);
#pragma unroll
        for (int j = 0; j < 8; ++j) o.h[j] = f2bf(av[j]);
      }
      *(uint4*)(&As[r][acol]) = o.u;
    }
    // stage Bg/Bu transposed: load 2 k-rows of 8 n (f32), pack bf16 pairs
    {
      const float* g0 = wg_base + (size_t)(kt + k2) * I_DIM + n8;
      const float* u0 = wu_base + (size_t)(kt + k2) * I_DIM + n8;
      float ga[8], gb[8], ua[8], ub[8];
      *(float4*)&ga[0] = *(const float4*)(g0);
      *(float4*)&ga[4] = *(const float4*)(g0 + 4);
      *(float4*)&gb[0] = *(const float4*)(g0 + I_DIM);
      *(float4*)&gb[4] = *(const float4*)(g0 + I_DIM + 4);
      *(float4*)&ua[0] = *(const float4*)(u0);
      *(float4*)&ua[4] = *(const float4*)(u0 + 4);
      *(float4*)&ub[0] = *(const float4*)(u0 + I_DIM);
      *(float4*)&ub[4] = *(const float4*)(u0 + I_DIM + 4);
#pragma unroll
      for (int j = 0; j < 8; ++j) {
        *(unsigned int*)(&Bg[n8 + j][k2]) =
            (unsigned int)f2bf(ga[j]) | ((unsigned int)f2bf(gb[j]) << 16);
        *(unsigned int*)(&Bu[n8 + j][k2]) =
            (unsigned int)f2bf(ua[j]) | ((unsigned int)f2bf(ub[j]) << 16);
      }
    }
    __syncthreads();
#pragma unroll
    for (int ks = 0; ks < 64; ks += 32) {
      bf16x8 af[2], bgf[2], buf2[2];
#pragma unroll
      for (int mi = 0; mi < 2; ++mi)
        af[mi] = *(const bf16x8*)(&As[msub + mi * 16 + fm][ks + fq * 8]);
#pragma unroll
      for (int ni = 0; ni < 2; ++ni) {
        bgf[ni] = *(const bf16x8*)(&Bg[nsub + ni * 16 + fm][ks + fq * 8]);
        buf2[ni] = *(const bf16x8*)(&Bu[nsub + ni * 16 + fm][ks + fq * 8]);
      }
#pragma unroll
      for (int mi = 0; mi < 2; ++mi)
#pragma unroll
        for (int ni = 0; ni < 2; ++ni) {
          accg[mi][ni] = __builtin_amdgcn_mfma_f32_16x16x32_bf16(af[mi], bgf[ni], accg[mi][ni], 0, 0, 0);
          accu[mi][ni] = __builtin_amdgcn_mfma_f32_16x16x32_bf16(af[mi], buf2[ni], accu[mi][ni], 0, 0, 0);
        }
    }
    __syncthreads();
  }
  // epilogue: silu(g)*u -> bf16 act[p, n]
#pragma unroll
  for (int mi = 0; mi < 2; ++mi) {
#pragma unroll
    for (int r = 0; r < 4; ++r) {
      int ml = msub + mi * 16 + fq * 4 + r;
      int p = rowp[ml];
      if (p < 0) continue;
      size_t base = (size_t)p * I_DIM + n0 + nsub + fm;
#pragma unroll
      for (int ni = 0; ni < 2; ++ni) {
        float g = accg[mi][ni][r];
        float u = accu[mi][ni][r];
        float h = g / (1.f + __expf(-g)) * u;
        act[base + ni * 16] = f2bf(h);
      }
    }
  }
}

// ---------------- Down-projection + weighted scatter-add into d_out ----------------
__global__ __launch_bounds__(256) void moe_down_kernel(
    const unsigned short* __restrict__ act,  // [T*2, I] bf16
    const float* __restrict__ wo,            // [E,I,H] f32
    const int* __restrict__ counts,
    const int* __restrict__ entries,
    const float* __restrict__ entry_w,
    float* __restrict__ out)                 // [T,H] f32 (d_out head)
{
  const int e = blockIdx.z;
  const int cnt = counts[e];
  const int m0 = blockIdx.y * 64;
  if (m0 >= cnt) return;
  const int n0 = blockIdx.x * 64;
  const int tid = threadIdx.x;

  __shared__ __align__(16) unsigned short As[64][72];
  __shared__ __align__(16) unsigned short Bt[64][72];
  __shared__ int rowp[64];
  __shared__ float roww[64];

  if (tid < 64) {
    int idx = m0 + tid;
    rowp[tid] = (idx < cnt) ? entries[e * T_TOK + idx] : -1;
    roww[tid] = (idx < cnt) ? entry_w[e * T_TOK + idx] : 0.f;
  }
  __syncthreads();

  const float* wo_base = wo + (size_t)e * I_DIM * H_DIM + n0;

  f32x4 acc[2][2];
#pragma unroll
  for (int i = 0; i < 2; ++i)
#pragma unroll
    for (int j = 0; j < 2; ++j) acc[i][j] = (f32x4){0.f, 0.f, 0.f, 0.f};

  const int wv = tid >> 6;
  const int lane = tid & 63;
  const int msub = (wv >> 1) * 32;
  const int nsub = (wv & 1) * 32;
  const int fm = lane & 15;
  const int fq = lane >> 4;

  const int arow = tid >> 3;
  const int acol = (tid & 7) * 8;
  const int k2 = (tid >> 3) * 2;
  const int n8 = (tid & 7) * 8;

  for (int kt = 0; kt < I_DIM; kt += 64) {
    // stage A from act (bf16 already)
#pragma unroll
    for (int it = 0; it < 2; ++it) {
      int r = arow + it * 32;
      int p = rowp[r];
      uint4 v = {0u, 0u, 0u, 0u};
      if (p >= 0) v = *(const uint4*)(act + (size_t)p * I_DIM + kt + acol);
      *(uint4*)(&As[r][acol]) = v;
    }
    // stage B transposed (f32 -> bf16 pairs)
    {
      const float* b0 = wo_base + (size_t)(kt + k2) * H_DIM + n8;
      float ba[8], bb[8];
      *(float4*)&ba[0] = *(const float4*)(b0);
      *(float4*)&ba[4] = *(const float4*)(b0 + 4);
      *(float4*)&bb[0] = *(const float4*)(b0 + H_DIM);
      *(float4*)&bb[4] = *(const float4*)(b0 + H_DIM + 4);
#pragma unroll
      for (int j = 0; j < 8; ++j)
        *(unsigned int*)(&Bt[n8 + j][k2]) =
            (unsigned int)f2bf(ba[j]) | ((unsigned int)f2bf(bb[j]) << 16);
    }
    __syncthreads();
#pragma unroll
    for (int ks = 0; ks < 64; ks += 32) {
      bf16x8 af[2], bf[2];
#pragma unroll
      for (int mi = 0; mi < 2; ++mi)
        af[mi] = *(const bf16x8*)(&As[msub + mi * 16 + fm][ks + fq * 8]);
#pragma unroll
      for (int ni = 0; ni < 2; ++ni)
        bf[ni] = *(const bf16x8*)(&Bt[nsub + ni * 16 + fm][ks + fq * 8]);
#pragma unroll
      for (int mi = 0; mi < 2; ++mi)
#pragma unroll
        for (int ni = 0; ni < 2; ++ni)
          acc[mi][ni] = __builtin_amdgcn_mfma_f32_16x16x32_bf16(af[mi], bf[ni], acc[mi][ni], 0, 0, 0);
    }
    __syncthreads();
  }
#pragma unroll
  for (int mi = 0; mi < 2; ++mi) {
#pragma unroll
    for (int r = 0; r < 4; ++r) {
      int ml = msub + mi * 16 + fq * 4 + r;
      int p = rowp[ml];
      if (p < 0) continue;
      float w = roww[ml];
      int t = p >> 1;
      float* dst = out + (size_t)t * H_DIM + n0 + nsub + fm;
#pragma unroll
      for (int ni = 0; ni < 2; ++ni)
        atomicAdd(dst + ni * 16, acc[mi][ni][r] * w);
    }
  }
}

extern "C" void kernel_launch(void* const* d_in, const int* in_sizes, int n_in,
                              void* d_out, int out_size, void* d_ws, size_t ws_size,
                              hipStream_t stream) {
  const float* x   = (const float*)d_in[0];
  const float* wr  = (const float*)d_in[1];
  const float* wi0 = (const float*)d_in[2];
  const float* wi1 = (const float*)d_in[3];
  const float* wo  = (const float*)d_in[4];
  float* out = (float*)d_out;                       // [T,H] f32
  float* logits_out = out + (size_t)T_TOK * H_DIM;  // [T,E] f32

  char* w = (char*)d_ws;
  int* counts    = (int*)w;
  int* entries   = (int*)(w + 64);
  float* entry_w = (float*)(w + 64 + (size_t)E_NUM * T_TOK * 4);
  unsigned short* act =
      (unsigned short*)(w + 64 + 2 * (size_t)E_NUM * T_TOK * 4);  // [2T, I] bf16

  // zero the f32 accumulation target (d_out head) and the expert counters
  hipMemsetAsync(d_out, 0, (size_t)T_TOK * H_DIM * sizeof(float), stream);
  hipMemsetAsync(counts, 0, 64, stream);
  router_kernel<<<T_TOK, 256, 0, stream>>>(x, wr, logits_out, counts, entries, entry_w);
  moe_up_kernel<<<dim3(I_DIM / 64, T_TOK / 64, E_NUM), 256, 0, stream>>>(
      x, wi0, wi1, counts, entries, act);
  moe_down_kernel<<<dim3(H_DIM / 64, T_TOK / 64, E_NUM), 256, 0, stream>>>(
      act, wo, counts, entries, entry_w, out);
}